// Round 4
// baseline (184.445 us; speedup 1.0000x reference)
//
#include <hip/hip_runtime.h>

#define PI2_64 0.098174770424681038f   // 2*pi/64

// Sizes fixed: B=2, CI=CO=32, N=64, M=8.
// Freq map: t in [0,16): f = t (t<8) else t-16 (negative freqs 48+t mod 64).
// Tables: cs[m] = (cos, sin)(2*pi*m/64).

// ============ kA: fused forward z-DFT (64->8) + y-DFT (64->16) ==============
// grid 4096 = (b*32+ci)*64 + x ; block 256.
// Phase1: thread=(y 64, qp 4): z-pair quarters, 8 kz in regs, shfl reduce.
// Phase2: thread=(jp 8, kz 8, h 4): y-pair E/O + +-freq S-trick, shfl reduce.
__global__ __launch_bounds__(256) void k_fwd_zy(const float* __restrict__ x,
                                                float* __restrict__ z2) {
  __shared__ __align__(16) float sp[64 * 65];
  __shared__ __align__(8) float2 Zc[64 * 9];
  __shared__ __align__(8) float2 Ec[32 * 9], Oc[32 * 9];
  __shared__ __align__(8) float2 cs[64];
  int tid = threadIdx.x;

  const float4* xg = (const float4*)(x + (long)blockIdx.x * 4096);
#pragma unroll
  for (int j = 0; j < 4; ++j) {
    int idx = j * 256 + tid;
    float4 v = xg[idx];
    int flat = idx << 2;
    int y = flat >> 6, z = flat & 63;
    float* d = &sp[y * 65 + z];
    d[0] = v.x; d[1] = v.y; d[2] = v.z; d[3] = v.w;
  }
  if (tid < 64) {
    float s, c; __sincosf(PI2_64 * (float)tid, &s, &c);
    cs[tid] = make_float2(c, s);
  }
  __syncthreads();

  // ---- phase 1: z-DFT. Zr = sum e*c (+x0 +(-1)^k x32), Zi = -sum o*s ----
  {
    int y = tid >> 2, qp = tid & 3;
    const float* row = &sp[y * 65];
    float Sr[8] = {0,0,0,0,0,0,0,0}, So[8] = {0,0,0,0,0,0,0,0};
    int p0 = qp * 8 + 1, pend = (qp == 3) ? 32 : (p0 + 8);
    for (int p = p0; p < pend; ++p) {
      float a = row[p], b = row[64 - p];
      float e = a + b, o = a - b;
      Sr[0] += e;                    // k=0: c=1, s=0
      int m = p & 63;
#pragma unroll
      for (int k = 1; k < 8; ++k) {
        float2 t = cs[m];
        Sr[k] = fmaf(e, t.x, Sr[k]);
        So[k] = fmaf(o, t.y, So[k]);
        m = (m + p) & 63;
      }
    }
    if (qp == 3) {                   // singles z=0, z=32
      float x0 = row[0], x32 = row[32];
      float a = x0 + x32, b = x0 - x32;
#pragma unroll
      for (int k = 0; k < 8; ++k) Sr[k] += (k & 1) ? b : a;
    }
#pragma unroll
    for (int k = 0; k < 8; ++k) {
      Sr[k] += __shfl_xor(Sr[k], 1); So[k] += __shfl_xor(So[k], 1);
      Sr[k] += __shfl_xor(Sr[k], 2); So[k] += __shfl_xor(So[k], 2);
    }
    if (qp == 0) {
#pragma unroll
      for (int k = 0; k < 8; ++k) Zc[y * 9 + k] = make_float2(Sr[k], -So[k]);
    }
  }
  __syncthreads();

  // ---- y-pair E/O prepass ----
  if (tid < 248) {
    int yp = (tid >> 3) + 1, k = tid & 7;
    float2 a = Zc[yp * 9 + k], b = Zc[(64 - yp) * 9 + k];
    Ec[yp * 9 + k] = make_float2(a.x + b.x, a.y + b.y);
    Oc[yp * 9 + k] = make_float2(a.x - b.x, a.y - b.y);
  }
  __syncthreads();

  // ---- phase 2: y-DFT. A[+j]=(S1+S2, S3-S4), A[-j]=(S1-S2, S3+S4) ----
  {
    int jp = tid >> 5, kz = (tid >> 2) & 7, h = tid & 3;
    int j = jp + 1;
    float S1 = 0, S2 = 0, S3 = 0, S4 = 0, S0r = 0, S0i = 0;
    int p0 = h * 8 + 1, pend = (h == 3) ? 32 : (p0 + 8);
    int m = (j * p0) & 63;
    for (int yp = p0; yp < pend; ++yp) {
      float2 E = Ec[yp * 9 + kz], O = Oc[yp * 9 + kz];
      float2 t = cs[m];
      S1 = fmaf(E.x, t.x, S1);
      S2 = fmaf(O.y, t.y, S2);
      S3 = fmaf(E.y, t.x, S3);
      S4 = fmaf(O.x, t.y, S4);
      if (jp == 7) { S0r += E.x; S0i += E.y; }   // f=0 accumulation
      m = (m + j) & 63;
    }
    if (h == 3) {                    // singles y=0, y=32: s=0 -> into S1/S3
      float2 z0 = Zc[kz], z32 = Zc[32 * 9 + kz];
      float sg = (j & 1) ? -1.f : 1.f;
      S1 += z0.x + sg * z32.x;
      S3 += z0.y + sg * z32.y;
      if (jp == 7) { S0r += z0.x + z32.x; S0i += z0.y + z32.y; }
    }
    S1 += __shfl_xor(S1, 1); S1 += __shfl_xor(S1, 2);
    S2 += __shfl_xor(S2, 1); S2 += __shfl_xor(S2, 2);
    S3 += __shfl_xor(S3, 1); S3 += __shfl_xor(S3, 2);
    S4 += __shfl_xor(S4, 1); S4 += __shfl_xor(S4, 2);
    S0r += __shfl_xor(S0r, 1); S0r += __shfl_xor(S0r, 2);
    S0i += __shfl_xor(S0i, 1); S0i += __shfl_xor(S0i, 2);
    if (h == 0) {
      float2* gz = (float2*)z2 + (long)blockIdx.x * 128;
      float2 vA = (jp < 7) ? make_float2(S1 + S2, S3 - S4) : make_float2(S0r, S0i);
      int tA = (jp < 7) ? j : 0;
      float2 vB = make_float2(S1 - S2, S3 + S4);   // f = -j -> t = 16-j
      gz[tA * 8 + kz] = vA;
      gz[(16 - j) * 8 + kz] = vB;
    }
  }
}

// ============ A3: x-transform (64 x -> 16 t), REAL part only ================
// grid 1024 (= B*CI * 16 u), block 128 = (t 16)*(v 8).  (unchanged, verified)
__global__ __launch_bounds__(128) void k_fwd_x(const float* __restrict__ z2,
                                               float* __restrict__ xc) {
  __shared__ __align__(16) float s[64 * 16];
  int tid = threadIdx.x;
  int bi = blockIdx.x >> 4;
  int u = blockIdx.x & 15;
  const float* src = z2 + (long)bi * 16384 + u * 16;
  {
    int xr = tid >> 1, c0 = (tid & 1) * 8;
    const float4* p = (const float4*)(src + xr * 256 + c0);
    float4* q = (float4*)(s + xr * 16 + c0);
    q[0] = p[0]; q[1] = p[1];
  }
  __syncthreads();
  int t = tid >> 3, v = tid & 7;
  int f = (t < 8) ? t : 48 + t;
  float bs, bc; __sincosf(-PI2_64 * (float)f, &bs, &bc);
  float wr = 1.f, wi = 0.f, acc = 0.f;
  for (int xx = 0; xx < 64; ++xx) {
    float zr = s[xx * 16 + v * 2], zi = s[xx * 16 + v * 2 + 1];
    acc += zr * wr - zi * wi;
    float nr = wr * bc - wi * bs;
    wi = wr * bs + wi * bc;
    wr = nr;
  }
  xc[(long)bi * 2048 + t * 128 + u * 8 + v] = acc;
}

// ============ B: channel mix, u-paired for full-line weight reads ===========
// grid 256 = (b 2)*(t 16)*(uh 8), block 256 = (o 32)*(v 8); u = 2*uh, 2*uh+1
__global__ __launch_bounds__(256) void k_mix(const float* __restrict__ xc,
    const float* __restrict__ w1r, const float* __restrict__ w1i,
    const float* __restrict__ w2r, const float* __restrict__ w2i,
    const float* __restrict__ w3r, const float* __restrict__ w3i,
    const float* __restrict__ w4r, const float* __restrict__ w4i,
    float* __restrict__ outm) {
  __shared__ float sx[2 * 256];
  int tid = threadIdx.x;
  int b = blockIdx.x >> 7;
  int t = (blockIdx.x >> 3) & 15;
  int uh = blockIdx.x & 7;
  int u0 = uh * 2;
  {
    int i = tid >> 3, v = tid & 7;
    long base = (long)(b * 32 + i) * 2048 + t * 128;
    sx[tid]       = xc[base + u0 * 8 + v];
    sx[256 + tid] = xc[base + (u0 + 1) * 8 + v];
  }
  __syncthreads();
  const float* wr_ = (t < 8) ? ((u0 < 8) ? w1r : w3r) : ((u0 < 8) ? w2r : w4r);
  const float* wi_ = (t < 8) ? ((u0 < 8) ? w1i : w3i) : ((u0 < 8) ? w2i : w4i);
  int tm = t & 7, um0 = u0 & 7;
  int o = tid >> 3, v = tid & 7;
  long woff = (long)o * 512 + tm * 64 + um0 * 8 + v;
  float ar0 = 0, ai0 = 0, ar1 = 0, ai1 = 0;
#pragma unroll 4
  for (int i = 0; i < 32; ++i) {
    float x0 = sx[i * 8 + v], x1 = sx[256 + i * 8 + v];
    long wo = woff + (long)i * 16384;
    ar0 = fmaf(x0, wr_[wo], ar0);
    ai0 = fmaf(x0, wi_[wo], ai0);
    ar1 = fmaf(x1, wr_[wo + 8], ar1);
    ai1 = fmaf(x1, wi_[wo + 8], ai1);
  }
  long oi = (long)(b * 32 + o) * 2048 + t * 128 + u0 * 8 + v;
  ((float2*)outm)[oi] = make_float2(ar0, ai0);
  ((float2*)outm)[oi + 8] = make_float2(ar1, ai1);
}

// ============ kC: fused inverse x+y+z with +-freq pairing ===================
// grid 4096 = bo*64 + x ; block 256.
__global__ __launch_bounds__(256) void k_inv_xyz(const float* __restrict__ outm,
                                                 float* __restrict__ out) {
  __shared__ __align__(8) float2 E1[9 * 128], O1[9 * 128];  // [j][u*8+v]
  __shared__ __align__(16) float2 Y1c[128];                 // [u][v]
  __shared__ __align__(16) float2 Y2c[64 * 10];             // [y][v pad10]
  __shared__ __align__(8) float2 cs[64];
  __shared__ float rc[64], rs[64];
  __shared__ __align__(16) float2 ct3[512];                 // [zq][v][i]
  int tid = threadIdx.x;
  int bo = blockIdx.x >> 6, xx = blockIdx.x & 63;

  if (tid < 64) {
    float s, c; __sincosf(PI2_64 * (float)tid, &s, &c);
    cs[tid] = make_float2(c, s); rc[tid] = c; rs[tid] = s;
  }
#pragma unroll
  for (int it = 0; it < 2; ++it) {
    int idx = tid + it * 256;
    int zq = idx >> 7, rem = idx & 127, v = rem >> 4, i = rem & 15;
    int m = (v * (zq * 16 + i)) & 63;
    float s, c; __sincosf(PI2_64 * (float)m, &s, &c);
    ct3[idx] = make_float2(c, s);
  }
  // prepass: E/O over x-freq pairs, straight from global (L2-hot)
  const float2* pg = (const float2*)outm + (long)bo * 2048;
  for (int it = 0; it < 5; ++it) {
    int idx = tid + it * 256;
    if (idx < 1152) {
      int j = idx >> 7, uv = idx & 127;
      float2 pA = pg[j * 128 + uv];
      float2 E, O;
      if (j == 0)      { E = pA; O = make_float2(0.f, 0.f); }
      else if (j == 8) { E = pA; O = make_float2(-pA.x, -pA.y); }
      else {
        float2 pB = pg[(16 - j) * 128 + uv];
        E = make_float2(pA.x + pB.x, pA.y + pB.y);
        O = make_float2(pA.x - pB.x, pA.y - pB.y);
      }
      E1[idx] = E; O1[idx] = O;
    }
  }
  __syncthreads();

  // C1: x-expand at this xx. contribution: (Er*c - Oi*s, Ei*c + Or*s)
  {
    int u = tid >> 4, v = (tid >> 1) & 7, h = tid & 1;
    int uv = u * 8 + v;
    float Yr = 0, Yi = 0;
    int j0 = h ? 5 : 0, j1 = h ? 9 : 5;
    for (int j = j0; j < j1; ++j) {
      float2 E = E1[(j << 7) + uv], O = O1[(j << 7) + uv];
      float2 t = cs[(j * xx) & 63];          // uniform per block: broadcast
      Yr += E.x * t.x - O.y * t.y;
      Yi += E.y * t.x + O.x * t.y;
    }
    Yr += __shfl_xor(Yr, 1); Yi += __shfl_xor(Yi, 1);
    if (h == 0) Y1c[uv] = make_float2(Yr, Yi);
  }
  __syncthreads();

  // C2: y-expand, E/O computed on the fly (broadcast reads), scale folded in
  {
    int y = tid & 63, vq = tid >> 6, v0 = vq * 2;
    float4 A0 = *(const float4*)(&Y1c[v0]);      // j=0 (u=0)
    float Yr0 = A0.x, Yi0 = A0.y, Yr1 = A0.z, Yi1 = A0.w;
#pragma unroll
    for (int j = 1; j < 8; ++j) {
      float4 Aj = *(const float4*)(&Y1c[j * 8 + v0]);
      float4 Bj = *(const float4*)(&Y1c[(16 - j) * 8 + v0]);
      int m = (j * y) & 63;
      float c = rc[m], s = rs[m];
      float E0r = Aj.x + Bj.x, E0i = Aj.y + Bj.y;
      float O0r = Aj.x - Bj.x, O0i = Aj.y - Bj.y;
      float E1r = Aj.z + Bj.z, E1i = Aj.w + Bj.w;
      float O1r = Aj.z - Bj.z, O1i = Aj.w - Bj.w;
      Yr0 += E0r * c - O0i * s; Yi0 += E0i * c + O0r * s;
      Yr1 += E1r * c - O1i * s; Yi1 += E1i * c + O1r * s;
    }
    {  // j=8 (u=8, f=-8): E=A, O=-A
      float4 Aj = *(const float4*)(&Y1c[64 + v0]);
      int m = (y * 8) & 63;
      float c = rc[m], s = rs[m];
      Yr0 += Aj.x * c + Aj.y * s; Yi0 += Aj.y * c - Aj.x * s;
      Yr1 += Aj.z * c + Aj.w * s; Yi1 += Aj.w * c - Aj.z * s;
    }
    const float sc = 1.f / 262144.f;
    *(float4*)(&Y2c[y * 10 + v0]) =
        make_float4(Yr0 * sc, Yi0 * sc, Yr1 * sc, Yi1 * sc);
  }
  __syncthreads();

  // C3: z-expand + Re. thread=(zq 4, y 64): own row in regs, bcast twiddles
  {
    int y = tid & 63, zq = tid >> 6;
    const float4* rowp = (const float4*)(&Y2c[y * 10]);
    float4 r0 = rowp[0], r1 = rowp[1], r2 = rowp[2], r3 = rowp[3];
    float Yr[8] = {r0.x, r0.z, r1.x, r1.z, r2.x, r2.z, r3.x, r3.z};
    float Yi[8] = {r0.y, r0.w, r1.y, r1.w, r2.y, r2.w, r3.y, r3.w};
    float acc[16];
#pragma unroll
    for (int i = 0; i < 16; ++i) acc[i] = 0.f;
#pragma unroll
    for (int v = 0; v < 8; ++v) {
      const float2* ct = &ct3[(zq * 8 + v) * 16];
#pragma unroll
      for (int i = 0; i < 16; ++i) {
        float2 t = ct[i];
        acc[i] = fmaf(Yr[v], t.x, fmaf(-Yi[v], t.y, acc[i]));
      }
    }
    float* ob = out + (long)blockIdx.x * 4096 + y * 64 + zq * 16;
#pragma unroll
    for (int q = 0; q < 4; ++q)
      ((float4*)ob)[q] = make_float4(acc[q*4], acc[q*4+1], acc[q*4+2], acc[q*4+3]);
  }
}

extern "C" void kernel_launch(void* const* d_in, const int* in_sizes, int n_in,
                              void* d_out, int out_size, void* d_ws, size_t ws_size,
                              hipStream_t stream) {
  (void)in_sizes; (void)n_in; (void)out_size; (void)ws_size;
  const float* x   = (const float*)d_in[0];
  const float* w1r = (const float*)d_in[1];
  const float* w1i = (const float*)d_in[2];
  const float* w2r = (const float*)d_in[3];
  const float* w2i = (const float*)d_in[4];
  const float* w3r = (const float*)d_in[5];
  const float* w3i = (const float*)d_in[6];
  const float* w4r = (const float*)d_in[7];
  const float* w4i = (const float*)d_in[8];
  float* out = (float*)d_out;
  float* ws = (float*)d_ws;

  float* z2   = ws;                 // 1,048,576 floats
  float* xc   = ws + 1048576;       //   131,072 floats
  float* outm = ws + 1179648;       //   262,144 floats

  k_fwd_zy <<<dim3(4096), dim3(256), 0, stream>>>(x, z2);
  k_fwd_x  <<<dim3(1024), dim3(128), 0, stream>>>(z2, xc);
  k_mix    <<<dim3(256),  dim3(256), 0, stream>>>(xc, w1r, w1i, w2r, w2i,
                                                  w3r, w3i, w4r, w4i, outm);
  k_inv_xyz<<<dim3(4096), dim3(256), 0, stream>>>(outm, out);
}

// Round 5
// 183.583 us; speedup vs baseline: 1.0047x; 1.0047x over previous
//
#include <hip/hip_runtime.h>

#define PI2_64 0.098174770424681038f   // 2*pi/64

// Sizes fixed: B=2, CI=CO=32, N=64, M=8.
// Freq map: t in [0,16): f = t (t<8) else t-16.
// Forward twiddle e^{-i*2pi*m/64}; inverse e^{+i*2pi*m/64}.

// ============ kA: fused forward z-DFT (64->8) + y-DFT (64->16) ==============
// grid 4096 = (b*32+ci)*64 + x ; block 256.
// Phase1: lane=(y 64, zq 4): 16 z in regs, 8 rotation chains, shfl over zq.
// Phase2: lane=(jp 8, kz 8, h 4): E/O inline + +-freq trick, rot twiddles.
__global__ __launch_bounds__(256) void k_fwd_zy(const float* __restrict__ x,
                                                float* __restrict__ z2) {
  __shared__ __align__(16) float sp[64 * 68];     // plane [y][z], pad 68
  __shared__ __align__(8) float2 Zs[64 * 9];      // [y][kz], pad 9
  int tid = threadIdx.x;

  const float4* xg = (const float4*)(x + (long)blockIdx.x * 4096);
#pragma unroll
  for (int r = 0; r < 4; ++r) {
    int q = tid + 256 * r;
    float4 v = xg[q];
    int fl = q << 2;
    int y = fl >> 6, z = fl & 63;
    float* d = &sp[y * 68 + z];
    d[0] = v.x; d[1] = v.y; d[2] = v.z; d[3] = v.w;
  }
  __syncthreads();

  // ---- phase 1: z-DFT, Z[y][k] = sum_z x*e^{-i 2pi z k/64} ----
  {
    int y = tid >> 2, zq = tid & 3;
    const float4* row = (const float4*)(&sp[y * 68 + zq * 16]);
    float4 a0 = row[0], a1 = row[1], a2 = row[2], a3 = row[3];
    float xr[16] = {a0.x,a0.y,a0.z,a0.w, a1.x,a1.y,a1.z,a1.w,
                    a2.x,a2.y,a2.z,a2.w, a3.x,a3.y,a3.z,a3.w};
    float cr[8], ci[8], sc[8], ss[8];
#pragma unroll
    for (int k = 0; k < 8; ++k) {
      int m = (k * zq) & 3;                 // start twiddle = (-i)^(k*zq), exact
      cr[k] = (m == 0) ? 1.f : ((m == 2) ? -1.f : 0.f);
      ci[k] = (m == 1) ? -1.f : ((m == 3) ? 1.f : 0.f);
      float s, c; __sincosf(PI2_64 * (float)k, &s, &c);
      sc[k] = c; ss[k] = s;                 // step = e^{-i 2pi k/64} = (c, -s)
    }
    float Zr[8] = {0,0,0,0,0,0,0,0}, Zi[8] = {0,0,0,0,0,0,0,0};
#pragma unroll
    for (int i = 0; i < 16; ++i) {
      float xv = xr[i];
#pragma unroll
      for (int k = 0; k < 8; ++k) {
        Zr[k] = fmaf(xv, cr[k], Zr[k]);
        Zi[k] = fmaf(xv, ci[k], Zi[k]);
        float nr = cr[k] * sc[k] + ci[k] * ss[k];   // *(c - i s)
        ci[k] = ci[k] * sc[k] - cr[k] * ss[k];
        cr[k] = nr;
      }
    }
#pragma unroll
    for (int k = 0; k < 8; ++k) {
      Zr[k] += __shfl_xor(Zr[k], 1); Zr[k] += __shfl_xor(Zr[k], 2);
      Zi[k] += __shfl_xor(Zi[k], 1); Zi[k] += __shfl_xor(Zi[k], 2);
    }
    if (zq == 0) {
#pragma unroll
      for (int k = 0; k < 8; ++k) Zs[y * 9 + k] = make_float2(Zr[k], Zi[k]);
    }
  }
  __syncthreads();

  // ---- phase 2: y-DFT with E/O + +-j trick ----
  {
    int jp = tid >> 5, kz = (tid >> 2) & 7, h = tid & 3;
    int j = jp + 1;
    float S1 = 0, S2 = 0, S3 = 0, S4 = 0, S0r = 0, S0i = 0;
    int p0 = 8 * h + 1, pend = (h == 3) ? 32 : (p0 + 8);
    float c, s, stc, sts;
    __sincosf(PI2_64 * (float)((j * p0) & 63), &s, &c);
    __sincosf(PI2_64 * (float)j, &sts, &stc);
    for (int p = p0; p < pend; ++p) {
      float2 za = Zs[p * 9 + kz], zb = Zs[(64 - p) * 9 + kz];
      float Ex = za.x + zb.x, Ey = za.y + zb.y;
      float Ox = za.x - zb.x, Oy = za.y - zb.y;
      S1 = fmaf(Ex, c, S1); S2 = fmaf(Oy, s, S2);
      S3 = fmaf(Ey, c, S3); S4 = fmaf(Ox, s, S4);
      if (jp == 7) { S0r += Ex; S0i += Ey; }
      float nc = c * stc - s * sts; s = c * sts + s * stc; c = nc;
    }
    if (h == 3) {
      float2 z0 = Zs[kz], z32 = Zs[32 * 9 + kz];
      float sg = (j & 1) ? -1.f : 1.f;
      S1 += z0.x + sg * z32.x; S3 += z0.y + sg * z32.y;
      if (jp == 7) { S0r += z0.x + z32.x; S0i += z0.y + z32.y; }
    }
    S1 += __shfl_xor(S1, 1); S1 += __shfl_xor(S1, 2);
    S2 += __shfl_xor(S2, 1); S2 += __shfl_xor(S2, 2);
    S3 += __shfl_xor(S3, 1); S3 += __shfl_xor(S3, 2);
    S4 += __shfl_xor(S4, 1); S4 += __shfl_xor(S4, 2);
    S0r += __shfl_xor(S0r, 1); S0r += __shfl_xor(S0r, 2);
    S0i += __shfl_xor(S0i, 1); S0i += __shfl_xor(S0i, 2);
    if (h == 0) {
      float2* gz = (float2*)z2 + (long)blockIdx.x * 128;
      float2 vA = (jp < 7) ? make_float2(S1 + S2, S3 - S4) : make_float2(S0r, S0i);
      int tA = (jp < 7) ? j : 0;
      gz[tA * 8 + kz] = vA;
      gz[(16 - j) * 8 + kz] = make_float2(S1 - S2, S3 + S4);
    }
  }
}

// ============ A3: x-transform (64 x -> 16 t), REAL only, +-freq trick =======
// grid 1024 (= B*CI*16 u), block 128 = (jp 8, v 8, h 2).
__global__ __launch_bounds__(128) void k_fwd_x(const float* __restrict__ z2,
                                               float* __restrict__ xc) {
  __shared__ __align__(16) float2 Zs[64 * 10];    // [x][v], pad 10
  int tid = threadIdx.x;
  int bi = blockIdx.x >> 4;
  int u = blockIdx.x & 15;
  const float4* src = (const float4*)(z2 + (long)bi * 16384 + u * 16);
#pragma unroll
  for (int r = 0; r < 2; ++r) {
    int q = tid + 128 * r;
    int xx = q >> 2, pt = q & 3;
    float4 v = src[xx * 64 + pt];
    *(float4*)((float*)Zs + xx * 20 + pt * 4) = v;
  }
  __syncthreads();
  int jp = tid >> 4, v = (tid >> 1) & 7, h = tid & 1;
  int j = jp + 1;
  float S1 = 0, S2 = 0, S0 = 0;
  int p0 = 16 * h + 1, pend = (h == 1) ? 32 : 17;
  float c, s, stc, sts;
  __sincosf(PI2_64 * (float)((j * p0) & 63), &s, &c);
  __sincosf(PI2_64 * (float)j, &sts, &stc);
  for (int p = p0; p < pend; ++p) {
    float2 za = Zs[p * 10 + v], zb = Zs[(64 - p) * 10 + v];
    float Ex = za.x + zb.x, Oy = za.y - zb.y;
    S1 = fmaf(Ex, c, S1); S2 = fmaf(Oy, s, S2);
    if (jp == 7) S0 += Ex;
    float nc = c * stc - s * sts; s = c * sts + s * stc; c = nc;
  }
  if (h == 1) {
    float2 z0 = Zs[v], z32 = Zs[32 * 10 + v];
    float sg = (j & 1) ? -1.f : 1.f;
    S1 += z0.x + sg * z32.x;
    if (jp == 7) S0 += z0.x + z32.x;
  }
  S1 += __shfl_xor(S1, 1);
  S2 += __shfl_xor(S2, 1);
  S0 += __shfl_xor(S0, 1);
  if (h == 0) {
    float* xb = xc + (long)bi * 2048 + u * 8 + v;
    if (jp < 7) xb[j * 128] = S1 + S2; else xb[0] = S0;  // t=j / t=0
    xb[(16 - j) * 128] = S1 - S2;                        // t=16-j
  }
}

// ============ B: channel mix, u-paired for full-line weight reads ===========
// grid 256 = (b 2)*(t 16)*(uh 8), block 256 = (o 32)*(v 8); u = 2*uh, 2*uh+1
__global__ __launch_bounds__(256) void k_mix(const float* __restrict__ xc,
    const float* __restrict__ w1r, const float* __restrict__ w1i,
    const float* __restrict__ w2r, const float* __restrict__ w2i,
    const float* __restrict__ w3r, const float* __restrict__ w3i,
    const float* __restrict__ w4r, const float* __restrict__ w4i,
    float* __restrict__ outm) {
  __shared__ float sx[2 * 256];
  int tid = threadIdx.x;
  int b = blockIdx.x >> 7;
  int t = (blockIdx.x >> 3) & 15;
  int uh = blockIdx.x & 7;
  int u0 = uh * 2;
  {
    int i = tid >> 3, v = tid & 7;
    long base = (long)(b * 32 + i) * 2048 + t * 128;
    sx[tid]       = xc[base + u0 * 8 + v];
    sx[256 + tid] = xc[base + (u0 + 1) * 8 + v];
  }
  __syncthreads();
  const float* wr_ = (t < 8) ? ((u0 < 8) ? w1r : w3r) : ((u0 < 8) ? w2r : w4r);
  const float* wi_ = (t < 8) ? ((u0 < 8) ? w1i : w3i) : ((u0 < 8) ? w2i : w4i);
  int tm = t & 7, um0 = u0 & 7;
  int o = tid >> 3, v = tid & 7;
  long woff = (long)o * 512 + tm * 64 + um0 * 8 + v;
  float ar0 = 0, ai0 = 0, ar1 = 0, ai1 = 0;
#pragma unroll 4
  for (int i = 0; i < 32; ++i) {
    float x0 = sx[i * 8 + v], x1 = sx[256 + i * 8 + v];
    long wo = woff + (long)i * 16384;
    ar0 = fmaf(x0, wr_[wo], ar0);
    ai0 = fmaf(x0, wi_[wo], ai0);
    ar1 = fmaf(x1, wr_[wo + 8], ar1);
    ai1 = fmaf(x1, wi_[wo + 8], ai1);
  }
  long oi = (long)(b * 32 + o) * 2048 + t * 128 + u0 * 8 + v;
  ((float2*)outm)[oi] = make_float2(ar0, ai0);
  ((float2*)outm)[oi + 8] = make_float2(ar1, ai1);
}

// ============ kC: fused inverse x+y+z with +-freq pairing ===================
// grid 4096 = bo*64 + x ; block 256.
__global__ __launch_bounds__(256) void k_inv_xyz(const float* __restrict__ outm,
                                                 float* __restrict__ out) {
  __shared__ __align__(8) float2 E1[9 * 128], O1[9 * 128];  // [j][u*8+v]
  __shared__ __align__(16) float2 Y1c[128];                 // [u][v]
  __shared__ __align__(16) float2 Y2c[64 * 10];             // [y][v pad10]
  __shared__ __align__(8) float2 cs[64];
  __shared__ float rc[64], rs[64];
  int tid = threadIdx.x;
  int bo = blockIdx.x >> 6, xx = blockIdx.x & 63;

  if (tid < 64) {
    float s, c; __sincosf(PI2_64 * (float)tid, &s, &c);
    cs[tid] = make_float2(c, s); rc[tid] = c; rs[tid] = s;
  }
  // prepass: E/O over x-freq pairs, straight from global (L2-hot)
  const float2* pg = (const float2*)outm + (long)bo * 2048;
  for (int it = 0; it < 5; ++it) {
    int idx = tid + it * 256;
    if (idx < 1152) {
      int j = idx >> 7, uv = idx & 127;
      float2 pA = pg[j * 128 + uv];
      float2 E, O;
      if (j == 0)      { E = pA; O = make_float2(0.f, 0.f); }
      else if (j == 8) { E = pA; O = make_float2(-pA.x, -pA.y); }
      else {
        float2 pB = pg[(16 - j) * 128 + uv];
        E = make_float2(pA.x + pB.x, pA.y + pB.y);
        O = make_float2(pA.x - pB.x, pA.y - pB.y);
      }
      E1[idx] = E; O1[idx] = O;
    }
  }
  __syncthreads();

  // C1: x-expand at this xx. contribution: (Er*c - Oi*s, Ei*c + Or*s)
  {
    int u = tid >> 4, v = (tid >> 1) & 7, h = tid & 1;
    int uv = u * 8 + v;
    float Yr = 0, Yi = 0;
    int j0 = h ? 5 : 0, j1 = h ? 9 : 5;
    for (int j = j0; j < j1; ++j) {
      float2 E = E1[(j << 7) + uv], O = O1[(j << 7) + uv];
      float2 t = cs[(j * xx) & 63];          // uniform per block: broadcast
      Yr += E.x * t.x - O.y * t.y;
      Yi += E.y * t.x + O.x * t.y;
    }
    Yr += __shfl_xor(Yr, 1); Yi += __shfl_xor(Yi, 1);
    if (h == 0) Y1c[uv] = make_float2(Yr, Yi);
  }
  __syncthreads();

  // C2: y-expand, E/O on the fly (broadcast reads), 1/64^3 folded in
  {
    int y = tid & 63, vq = tid >> 6, v0 = vq * 2;
    float4 A0 = *(const float4*)(&Y1c[v0]);      // j=0 (u=0)
    float Yr0 = A0.x, Yi0 = A0.y, Yr1 = A0.z, Yi1 = A0.w;
#pragma unroll
    for (int j = 1; j < 8; ++j) {
      float4 Aj = *(const float4*)(&Y1c[j * 8 + v0]);
      float4 Bj = *(const float4*)(&Y1c[(16 - j) * 8 + v0]);
      int m = (j * y) & 63;
      float c = rc[m], s = rs[m];
      float E0r = Aj.x + Bj.x, E0i = Aj.y + Bj.y;
      float O0r = Aj.x - Bj.x, O0i = Aj.y - Bj.y;
      float E1r = Aj.z + Bj.z, E1i = Aj.w + Bj.w;
      float O1r = Aj.z - Bj.z, O1i = Aj.w - Bj.w;
      Yr0 += E0r * c - O0i * s; Yi0 += E0i * c + O0r * s;
      Yr1 += E1r * c - O1i * s; Yi1 += E1i * c + O1r * s;
    }
    {  // j=8 (u=8, f=-8): E=A, O=-A
      float4 Aj = *(const float4*)(&Y1c[64 + v0]);
      int m = (y * 8) & 63;
      float c = rc[m], s = rs[m];
      Yr0 += Aj.x * c + Aj.y * s; Yi0 += Aj.y * c - Aj.x * s;
      Yr1 += Aj.z * c + Aj.w * s; Yi1 += Aj.w * c - Aj.z * s;
    }
    const float sc = 1.f / 262144.f;
    *(float4*)(&Y2c[y * 10 + v0]) =
        make_float4(Yr0 * sc, Yi0 * sc, Yr1 * sc, Yi1 * sc);
  }
  __syncthreads();

  // C3: z-expand + Re. thread=(zq 4, y 64): row in regs, rotation twiddles
  {
    int y = tid & 63, zq = tid >> 6;
    const float4* rowp = (const float4*)(&Y2c[y * 10]);
    float4 r0 = rowp[0], r1 = rowp[1], r2 = rowp[2], r3 = rowp[3];
    float Yr[8] = {r0.x, r0.z, r1.x, r1.z, r2.x, r2.z, r3.x, r3.z};
    float Yi[8] = {r0.y, r0.w, r1.y, r1.w, r2.y, r2.w, r3.y, r3.w};
    float acc[16];
#pragma unroll
    for (int i = 0; i < 16; ++i) acc[i] = 0.f;
#pragma unroll
    for (int v = 0; v < 8; ++v) {
      int m = (v * zq) & 3;                 // start = i^(v*zq) (z0 = 16*zq), exact
      float c = (m == 0) ? 1.f : ((m == 2) ? -1.f : 0.f);
      float s = (m == 1) ? 1.f : ((m == 3) ? -1.f : 0.f);
      float stc, sts; __sincosf(PI2_64 * (float)v, &sts, &stc);  // e^{+i 2pi v/64}
      float yr = Yr[v], yi = Yi[v];
#pragma unroll
      for (int i = 0; i < 16; ++i) {
        acc[i] = fmaf(yr, c, fmaf(-yi, s, acc[i]));
        float nc = c * stc - s * sts; s = c * sts + s * stc; c = nc;
      }
    }
    float* ob = out + (long)blockIdx.x * 4096 + y * 64 + zq * 16;
#pragma unroll
    for (int q = 0; q < 4; ++q)
      ((float4*)ob)[q] = make_float4(acc[q*4], acc[q*4+1], acc[q*4+2], acc[q*4+3]);
  }
}

extern "C" void kernel_launch(void* const* d_in, const int* in_sizes, int n_in,
                              void* d_out, int out_size, void* d_ws, size_t ws_size,
                              hipStream_t stream) {
  (void)in_sizes; (void)n_in; (void)out_size; (void)ws_size;
  const float* x   = (const float*)d_in[0];
  const float* w1r = (const float*)d_in[1];
  const float* w1i = (const float*)d_in[2];
  const float* w2r = (const float*)d_in[3];
  const float* w2i = (const float*)d_in[4];
  const float* w3r = (const float*)d_in[5];
  const float* w3i = (const float*)d_in[6];
  const float* w4r = (const float*)d_in[7];
  const float* w4i = (const float*)d_in[8];
  float* out = (float*)d_out;
  float* ws = (float*)d_ws;

  float* z2   = ws;                 // 1,048,576 floats
  float* xc   = ws + 1048576;       //   131,072 floats
  float* outm = ws + 1179648;       //   262,144 floats

  k_fwd_zy <<<dim3(4096), dim3(256), 0, stream>>>(x, z2);
  k_fwd_x  <<<dim3(1024), dim3(128), 0, stream>>>(z2, xc);
  k_mix    <<<dim3(256),  dim3(256), 0, stream>>>(xc, w1r, w1i, w2r, w2i,
                                                  w3r, w3i, w4r, w4i, outm);
  k_inv_xyz<<<dim3(4096), dim3(256), 0, stream>>>(outm, out);
}